// Round 17
// baseline (216.653 us; speedup 1.0000x reference)
//
#include <hip/hip_runtime.h>

typedef __attribute__((ext_vector_type(8))) short short8;
typedef __attribute__((ext_vector_type(4))) short short4v;
typedef __attribute__((ext_vector_type(4))) float float4v;

#define DEV static __device__ __forceinline__

DEV float b2f(unsigned short u) { return __uint_as_float(((unsigned)u) << 16); }
DEV unsigned short f2b(float f) {
  return __builtin_bit_cast(unsigned short, static_cast<__bf16>(f));
}

#define LOG2E 1.44269504088896340736f
#define QSCALE 0.17677669529663687f  // 32^-0.5

// ws layout (2-byte units):
// [0, 65536)      weights bf16, lane-ordered fragments:
//                 [m:{q,k,v,proj}][h][kt][dc][lane][8]  (each fragment = contiguous 1KB)
//                 m=0 (W_q) pre-scaled by QSCALE*LOG2E
// [65536, 81920)  biasM bf16 [4][64 q-row][64 key] row-major, pre-scaled by LOG2E
// [81920, +33.5M) comb2 bf16 [1024 wm][4 h][4 ci][4 ri][64 lane][4 j] = (mask+bias)*LOG2E
#define COMB2_OFF 81920
#define COMB2_SHORTS (1024u * 4u * 4096u)

__global__ void prep_kernel(const float* __restrict__ qkvw, const float* __restrict__ projw,
                            const float* __restrict__ btab, const int* __restrict__ ridx,
                            unsigned short* __restrict__ ws) {
  int t = blockIdx.x * blockDim.x + threadIdx.x;
  int nt = gridDim.x * blockDim.x;
  for (int i = t; i < 65536; i += nt) {
    int m = i >> 14, r = i & 16383;
    int e = r & 7, lane = (r >> 3) & 63, dc = (r >> 9) & 1, kt = (r >> 10) & 3, h = r >> 12;
    int row = h * 32 + dc * 16 + (lane & 15);
    int col = kt * 32 + (lane >> 4) * 8 + e;
    float v;
    if (m == 3) {
      v = projw[row * 128 + col];
    } else {
      v = qkvw[(m * 128 + row) * 128 + col];
      if (m == 0) v *= QSCALE * LOG2E;
    }
    ws[i] = f2b(v);
  }
  for (int i = t; i < 16384; i += nt) {
    int h = i >> 12, r = i & 4095;
    ws[65536 + i] = f2b(btab[ridx[r] * 4 + h] * LOG2E);
  }
}

// comb2[wm][h][ci][ri][lane][j] = bf16((mask[wm][row][key] + bias_h[row][key]) * LOG2E)
// with row = 16*ri + (lane&15), key = 16*ci + 4*(lane>>4) + j
__global__ void prep2_kernel(const float* __restrict__ mask, const float* __restrict__ btab,
                             const int* __restrict__ ridx, unsigned short* __restrict__ comb) {
  int wm = blockIdx.x, tid = threadIdx.x;
  const float* mrow = mask + (size_t)wm * 4096;
  unsigned short* cb = comb + (size_t)wm * 16384;
  for (int it = 0; it < 16; ++it) {
    int q4 = it * 256 + tid;            // short4 index 0..4095
    int lane = q4 & 63, ri = (q4 >> 6) & 3, ci = (q4 >> 8) & 3, h = q4 >> 10;
    int l15 = lane & 15, g = lane >> 4;
    int row = 16 * ri + l15;
    short4v v;
#pragma unroll
    for (int j = 0; j < 4; ++j) {
      int key = 16 * ci + 4 * g + j;
      float bias = btab[ridx[row * 64 + key] * 4 + h];
      v[j] = (short)f2b((mrow[row * 64 + key] + bias) * LOG2E);
    }
    *(short4v*)&cb[q4 * 4] = v;
  }
}

#define MFMA32 __builtin_amdgcn_mfma_f32_16x16x32_bf16

// ==================== EXPANDED: 16KB LDS, split passes, C from comb2 ========
__global__ __launch_bounds__(256, 3)
void win_attn_x(const float* __restrict__ x, const float* __restrict__ qkv_b,
                const float* __restrict__ proj_b, const unsigned short* __restrict__ ws,
                float* __restrict__ out) {
  // LDS (16 KB): x tile [64][128] bf16, swizzled (later attn_out)
  __shared__ short sm[8192];

  const int b = blockIdx.x;
  const int tid = threadIdx.x;
  const int h = tid >> 6;       // wave id == head
  const int lane = tid & 63;
  const int l15 = lane & 15;
  const int g = lane >> 4;
  const int g1 = g & 1, g2 = g >> 1;
  const int wm = b & 1023;

  // ---------------- phase 0: stage x only ------------------------------------
  {
    const float4* xw = (const float4*)(x + (size_t)b * 8192);
#pragma unroll
    for (int it = 0; it < 4; ++it) {
      int c = it * 256 + tid;           // 8-elem chunk 0..1023
      int row = c >> 4, ch = c & 15;
      float4 a0 = xw[c * 2], a1 = xw[c * 2 + 1];
      short8 v;
      v[0] = (short)f2b(a0.x); v[1] = (short)f2b(a0.y);
      v[2] = (short)f2b(a0.z); v[3] = (short)f2b(a0.w);
      v[4] = (short)f2b(a1.x); v[5] = (short)f2b(a1.y);
      v[6] = (short)f2b(a1.z); v[7] = (short)f2b(a1.w);
      *(short8*)&sm[row * 128 + ((ch ^ (row & 7)) << 3)] = v;
    }
  }
  __syncthreads();

#define LDA(kt, ri) (*(const short8*)&sm[(16 * (ri) + l15) * 128 + ((((kt)*4 + g) ^ (l15 & 7)) << 3)])
#define LW(mb, kt, dc) (*(const short8*)&ws[(mb) + (h << 12) + ((kt) << 10) + ((dc) << 9) + (lane << 3)])

  short8 kp8[4], qp8[4], vp8[2][2];

  // ---------------- pass k: k^T = Wk x^T + bk (swapped, kt looped) -----------
  {
    float4v acc[2][4];
#pragma unroll
    for (int dc = 0; dc < 2; ++dc) {
      float4v bk = *(const float4v*)&qkv_b[128 + h * 32 + dc * 16 + 4 * g];
#pragma unroll
      for (int ri = 0; ri < 4; ++ri)
#pragma unroll
        for (int j = 0; j < 4; ++j) acc[dc][ri][j] = bk[j];
    }
#pragma unroll 2
    for (int kt = 0; kt < 4; ++kt) {
      short8 af[4];
#pragma unroll
      for (int ri = 0; ri < 4; ++ri) af[ri] = LDA(kt, ri);
#pragma unroll
      for (int dc = 0; dc < 2; ++dc) {
        short8 wk = LW(16384, kt, dc);
#pragma unroll
        for (int ri = 0; ri < 4; ++ri) acc[dc][ri] = MFMA32(wk, af[ri], acc[dc][ri], 0, 0, 0);
      }
    }
#pragma unroll
    for (int ci = 0; ci < 4; ++ci)
#pragma unroll
      for (int dc = 0; dc < 2; ++dc)
#pragma unroll
        for (int j = 0; j < 4; ++j) kp8[ci][4 * dc + j] = (short)f2b(acc[dc][ci][j]);
  }

  // ---------------- pass v: v = x Wv^T + bv (unswapped, kt looped) -----------
  {
    float4v acc[2][4];
#pragma unroll
    for (int dt = 0; dt < 2; ++dt) {
      float bv = qkv_b[256 + h * 32 + dt * 16 + l15];
#pragma unroll
      for (int ri = 0; ri < 4; ++ri)
#pragma unroll
        for (int j = 0; j < 4; ++j) acc[dt][ri][j] = bv;
    }
#pragma unroll 2
    for (int kt = 0; kt < 4; ++kt) {
      short8 af[4];
#pragma unroll
      for (int ri = 0; ri < 4; ++ri) af[ri] = LDA(kt, ri);
#pragma unroll
      for (int dt = 0; dt < 2; ++dt) {
        short8 wv = LW(32768, kt, dt);
#pragma unroll
        for (int ri = 0; ri < 4; ++ri) acc[dt][ri] = MFMA32(af[ri], wv, acc[dt][ri], 0, 0, 0);
      }
    }
#pragma unroll
    for (int dt = 0; dt < 2; ++dt)
#pragma unroll
      for (int ci = 0; ci < 4; ++ci)
#pragma unroll
        for (int j = 0; j < 4; ++j)
          vp8[dt][ci >> 1][4 * (ci & 1) + j] = (short)f2b(acc[dt][ci][j]);
  }

  // ---------------- pass q (kt looped) ---------------------------------------
  {
    float4v acc[2][4];
#pragma unroll
    for (int dc = 0; dc < 2; ++dc) {
      float4v bb = *(const float4v*)&qkv_b[h * 32 + dc * 16 + 4 * g];
#pragma unroll
      for (int ri = 0; ri < 4; ++ri)
#pragma unroll
        for (int j = 0; j < 4; ++j) acc[dc][ri][j] = bb[j] * (QSCALE * LOG2E);
    }
#pragma unroll 2
    for (int kt = 0; kt < 4; ++kt) {
      short8 af[4];
#pragma unroll
      for (int ri = 0; ri < 4; ++ri) af[ri] = LDA(kt, ri);
#pragma unroll
      for (int dc = 0; dc < 2; ++dc) {
        short8 w = LW(0, kt, dc);
#pragma unroll
        for (int ri = 0; ri < 4; ++ri) acc[dc][ri] = MFMA32(w, af[ri], acc[dc][ri], 0, 0, 0);
      }
    }
#pragma unroll
    for (int ri = 0; ri < 4; ++ri)
#pragma unroll
      for (int dc = 0; dc < 2; ++dc)
#pragma unroll
        for (int j = 0; j < 4; ++j) qp8[ri][4 * dc + j] = (short)f2b(acc[dc][ri][j]);
  }

  // ---------------- S' = K Q^T (K=32) + comb2(global), exp2, PV (K=32) -------
  const unsigned short* cb = ws + COMB2_OFF + ((size_t)(wm * 4 + h)) * 4096;
  float4v ot[2][4];
#pragma unroll
  for (int dt = 0; dt < 2; ++dt)
#pragma unroll
    for (int ri = 0; ri < 4; ++ri) { ot[dt][ri][0]=0.f; ot[dt][ri][1]=0.f; ot[dt][ri][2]=0.f; ot[dt][ri][3]=0.f; }
  float rs[4];
#pragma unroll
  for (int ri = 0; ri < 4; ++ri) {
    float sum = 0.f;
    short4v pb[4];
#pragma unroll
    for (int ci = 0; ci < 4; ++ci) {
      short4v cm = *(const short4v*)&cb[(ci * 4 + ri) * 256 + lane * 4];
      float4v c;
#pragma unroll
      for (int j = 0; j < 4; ++j) c[j] = b2f((unsigned short)cm[j]);
      c = MFMA32(kp8[ci], qp8[ri], c, 0, 0, 0);
#pragma unroll
      for (int j = 0; j < 4; ++j) {
        float p = exp2f(c[j]);
        sum += p;
        pb[ci][j] = (short)f2b(p);
      }
    }
#pragma unroll
    for (int c2 = 0; c2 < 2; ++c2) {
      short8 pb8 = __builtin_shufflevector(pb[2 * c2], pb[2 * c2 + 1], 0, 1, 2, 3, 4, 5, 6, 7);
      ot[0][ri] = MFMA32(vp8[0][c2], pb8, ot[0][ri], 0, 0, 0);
      ot[1][ri] = MFMA32(vp8[1][c2], pb8, ot[1][ri], 0, 0, 0);
    }
    sum += __shfl_xor(sum, 16);
    sum += __shfl_xor(sum, 32);
    rs[ri] = __builtin_amdgcn_rcpf(sum);
  }

  __syncthreads();  // all waves done reading x from LDS
#pragma unroll
  for (int dt = 0; dt < 2; ++dt) {
    int ch = 4 * h + 2 * dt + g2;
#pragma unroll
    for (int ri = 0; ri < 4; ++ri) {
      int row = 16 * ri + l15;
      short4v pv;
#pragma unroll
      for (int j = 0; j < 4; ++j) pv[j] = (short)f2b(ot[dt][ri][j] * rs[ri]);
      *(short4v*)&sm[row * 128 + ((ch ^ (row & 7)) << 3) + 4 * g1] = pv;
    }
  }
  __syncthreads();

  // ---------------- output projection (kt looped), C init = proj_b -----------
  float4v po[2][4];
#pragma unroll
  for (int oc = 0; oc < 2; ++oc) {
    float4v pb4 = *(const float4v*)&proj_b[h * 32 + oc * 16 + 4 * g];
#pragma unroll
    for (int ri = 0; ri < 4; ++ri)
#pragma unroll
      for (int j = 0; j < 4; ++j) po[oc][ri][j] = pb4[j];
  }
#pragma unroll 2
  for (int kt = 0; kt < 4; ++kt) {
    short8 af[4];
#pragma unroll
    for (int ri = 0; ri < 4; ++ri) af[ri] = LDA(kt, ri);
#pragma unroll
    for (int oc = 0; oc < 2; ++oc) {
      short8 w = LW(49152, kt, oc);
#pragma unroll
      for (int ri = 0; ri < 4; ++ri)
        po[oc][ri] = MFMA32(w, af[ri], po[oc][ri], 0, 0, 0);
    }
  }
  float* ob = out + (size_t)b * 8192;
#pragma unroll
  for (int oc = 0; oc < 2; ++oc)
#pragma unroll
    for (int ri = 0; ri < 4; ++ri) {
      int row = 16 * ri + l15;
      float4 o = make_float4(po[oc][ri][0], po[oc][ri][1], po[oc][ri][2], po[oc][ri][3]);
      *(float4*)&ob[row * 128 + h * 32 + oc * 16 + 4 * g] = o;
    }
#undef LDA
#undef LW
}

// ==================== FALLBACK: R15 exact (48KB LDS, in-block combine) ======
__global__ __launch_bounds__(256, 3)
void win_attn_fb(const float* __restrict__ x, const float* __restrict__ mask,
                 const float* __restrict__ qkv_b, const float* __restrict__ proj_b,
                 const unsigned short* __restrict__ ws, float* __restrict__ out) {
  __shared__ short sm[24576];
  const int b = blockIdx.x;
  const int tid = threadIdx.x;
  const int h = tid >> 6;
  const int lane = tid & 63;
  const int l15 = lane & 15;
  const int g = lane >> 4;
  const int g1 = g & 1, g2 = g >> 1;
  const int wm = b & 1023;
  {
    const float4* xw = (const float4*)(x + (size_t)b * 8192);
#pragma unroll
    for (int it = 0; it < 4; ++it) {
      int c = it * 256 + tid;
      int row = c >> 4, ch = c & 15;
      float4 a0 = xw[c * 2], a1 = xw[c * 2 + 1];
      short8 v;
      v[0] = (short)f2b(a0.x); v[1] = (short)f2b(a0.y);
      v[2] = (short)f2b(a0.z); v[3] = (short)f2b(a0.w);
      v[4] = (short)f2b(a1.x); v[5] = (short)f2b(a1.y);
      v[6] = (short)f2b(a1.z); v[7] = (short)f2b(a1.w);
      *(short8*)&sm[row * 128 + ((ch ^ (row & 7)) << 3)] = v;
    }
    const float* mrow = mask + (size_t)wm * 4096;
    const unsigned short* bt = ws + 65536 + h * 4096;
    short* cs = &sm[8192 + h * 4096];
#pragma unroll 4
    for (int it = 0; it < 16; ++it) {
      int fi = it * 64 + lane;
      int row = fi >> 4, j0 = (fi & 15) << 2;
      float4 m4 = *(const float4*)&mrow[fi * 4];
      const unsigned short* bp = bt + row * 64 + j0;
      short4v v;
      v[0] = (short)f2b(__builtin_fmaf(m4.x, LOG2E, b2f(bp[0])));
      v[1] = (short)f2b(__builtin_fmaf(m4.y, LOG2E, b2f(bp[1])));
      v[2] = (short)f2b(__builtin_fmaf(m4.z, LOG2E, b2f(bp[2])));
      v[3] = (short)f2b(__builtin_fmaf(m4.w, LOG2E, b2f(bp[3])));
      *(short4v*)&cs[row * 64 + (((j0 >> 3) ^ (row & 7)) << 3) + (j0 & 7)] = v;
    }
  }
  __syncthreads();
#define LDA(kt, ri) (*(const short8*)&sm[(16 * (ri) + l15) * 128 + ((((kt)*4 + g) ^ (l15 & 7)) << 3)])
#define LW(mb, kt, dc) (*(const short8*)&ws[(mb) + (h << 12) + ((kt) << 10) + ((dc) << 9) + (lane << 3)])
  short8 kp8[4], qp8[4], vp8[2][2];
  {
    float4v acck[2][4], accv[2][4];
#pragma unroll
    for (int dc = 0; dc < 2; ++dc) {
      float4v bk = *(const float4v*)&qkv_b[128 + h * 32 + dc * 16 + 4 * g];
      float bv = qkv_b[256 + h * 32 + dc * 16 + l15];
#pragma unroll
      for (int ri = 0; ri < 4; ++ri)
#pragma unroll
        for (int j = 0; j < 4; ++j) { acck[dc][ri][j] = bk[j]; accv[dc][ri][j] = bv; }
    }
#pragma unroll 2
    for (int kt = 0; kt < 4; ++kt) {
      short8 af[4];
#pragma unroll
      for (int ri = 0; ri < 4; ++ri) af[ri] = LDA(kt, ri);
#pragma unroll
      for (int dc = 0; dc < 2; ++dc) {
        short8 wk = LW(16384, kt, dc);
#pragma unroll
        for (int ri = 0; ri < 4; ++ri) acck[dc][ri] = MFMA32(wk, af[ri], acck[dc][ri], 0, 0, 0);
      }
#pragma unroll
      for (int dt = 0; dt < 2; ++dt) {
        short8 wv = LW(32768, kt, dt);
#pragma unroll
        for (int ri = 0; ri < 4; ++ri) accv[dt][ri] = MFMA32(af[ri], wv, accv[dt][ri], 0, 0, 0);
      }
    }
#pragma unroll
    for (int ci = 0; ci < 4; ++ci)
#pragma unroll
      for (int dc = 0; dc < 2; ++dc)
#pragma unroll
        for (int j = 0; j < 4; ++j) kp8[ci][4 * dc + j] = (short)f2b(acck[dc][ci][j]);
#pragma unroll
    for (int dt = 0; dt < 2; ++dt)
#pragma unroll
      for (int ci = 0; ci < 4; ++ci)
#pragma unroll
        for (int j = 0; j < 4; ++j)
          vp8[dt][ci >> 1][4 * (ci & 1) + j] = (short)f2b(accv[dt][ci][j]);
  }
  {
    float4v acc[2][4];
#pragma unroll
    for (int dc = 0; dc < 2; ++dc) {
      float4v bb = *(const float4v*)&qkv_b[h * 32 + dc * 16 + 4 * g];
#pragma unroll
      for (int ri = 0; ri < 4; ++ri)
#pragma unroll
        for (int j = 0; j < 4; ++j) acc[dc][ri][j] = bb[j] * (QSCALE * LOG2E);
    }
#pragma unroll 2
    for (int kt = 0; kt < 4; ++kt) {
      short8 af[4];
#pragma unroll
      for (int ri = 0; ri < 4; ++ri) af[ri] = LDA(kt, ri);
#pragma unroll
      for (int dc = 0; dc < 2; ++dc) {
        short8 w = LW(0, kt, dc);
#pragma unroll
        for (int ri = 0; ri < 4; ++ri) acc[dc][ri] = MFMA32(w, af[ri], acc[dc][ri], 0, 0, 0);
      }
    }
#pragma unroll
    for (int ri = 0; ri < 4; ++ri)
#pragma unroll
      for (int dc = 0; dc < 2; ++dc)
#pragma unroll
        for (int j = 0; j < 4; ++j) qp8[ri][4 * dc + j] = (short)f2b(acc[dc][ri][j]);
  }
  const short* cs = &sm[8192 + h * 4096];
  float4v ot[2][4];
#pragma unroll
  for (int dt = 0; dt < 2; ++dt)
#pragma unroll
    for (int ri = 0; ri < 4; ++ri) { ot[dt][ri][0]=0.f; ot[dt][ri][1]=0.f; ot[dt][ri][2]=0.f; ot[dt][ri][3]=0.f; }
  float rs[4];
#pragma unroll
  for (int ri = 0; ri < 4; ++ri) {
    int row = 16 * ri + l15;
    float sum = 0.f;
    short4v pb[4];
#pragma unroll
    for (int ci = 0; ci < 4; ++ci) {
      short4v cm = *(const short4v*)&cs[row * 64 + (((2 * ci + g2) ^ (row & 7)) << 3) + 4 * g1];
      float4v c;
#pragma unroll
      for (int j = 0; j < 4; ++j) c[j] = b2f((unsigned short)cm[j]);
      c = MFMA32(kp8[ci], qp8[ri], c, 0, 0, 0);
#pragma unroll
      for (int j = 0; j < 4; ++j) {
        float p = exp2f(c[j]);
        sum += p;
        pb[ci][j] = (short)f2b(p);
      }
    }
#pragma unroll
    for (int c2 = 0; c2 < 2; ++c2) {
      short8 pb8 = __builtin_shufflevector(pb[2 * c2], pb[2 * c2 + 1], 0, 1, 2, 3, 4, 5, 6, 7);
      ot[0][ri] = MFMA32(vp8[0][c2], pb8, ot[0][ri], 0, 0, 0);
      ot[1][ri] = MFMA32(vp8[1][c2], pb8, ot[1][ri], 0, 0, 0);
    }
    sum += __shfl_xor(sum, 16);
    sum += __shfl_xor(sum, 32);
    rs[ri] = __builtin_amdgcn_rcpf(sum);
  }
  __syncthreads();
#pragma unroll
  for (int dt = 0; dt < 2; ++dt) {
    int ch = 4 * h + 2 * dt + g2;
#pragma unroll
    for (int ri = 0; ri < 4; ++ri) {
      int row = 16 * ri + l15;
      short4v pv;
#pragma unroll
      for (int j = 0; j < 4; ++j) pv[j] = (short)f2b(ot[dt][ri][j] * rs[ri]);
      *(short4v*)&sm[row * 128 + ((ch ^ (row & 7)) << 3) + 4 * g1] = pv;
    }
  }
  __syncthreads();
  float4v po[2][4];
#pragma unroll
  for (int oc = 0; oc < 2; ++oc) {
    float4v pb4 = *(const float4v*)&proj_b[h * 32 + oc * 16 + 4 * g];
#pragma unroll
    for (int ri = 0; ri < 4; ++ri)
#pragma unroll
      for (int j = 0; j < 4; ++j) po[oc][ri][j] = pb4[j];
  }
#pragma unroll 2
  for (int kt = 0; kt < 4; ++kt) {
    short8 af[4];
#pragma unroll
    for (int ri = 0; ri < 4; ++ri) af[ri] = LDA(kt, ri);
#pragma unroll
    for (int oc = 0; oc < 2; ++oc) {
      short8 w = LW(49152, kt, oc);
#pragma unroll
      for (int ri = 0; ri < 4; ++ri)
        po[oc][ri] = MFMA32(w, af[ri], po[oc][ri], 0, 0, 0);
    }
  }
  float* ob = out + (size_t)b * 8192;
#pragma unroll
  for (int oc = 0; oc < 2; ++oc)
#pragma unroll
    for (int ri = 0; ri < 4; ++ri) {
      int row = 16 * ri + l15;
      float4 o = make_float4(po[oc][ri][0], po[oc][ri][1], po[oc][ri][2], po[oc][ri][3]);
      *(float4*)&ob[row * 128 + h * 32 + oc * 16 + 4 * g] = o;
    }
#undef LDA
#undef LW
}

extern "C" void kernel_launch(void* const* d_in, const int* in_sizes, int n_in,
                              void* d_out, int out_size, void* d_ws, size_t ws_size,
                              hipStream_t stream) {
  const float* x      = (const float*)d_in[0];
  const float* mask   = (const float*)d_in[1];
  const float* qkv_w  = (const float*)d_in[2];
  const float* qkv_b  = (const float*)d_in[3];
  const float* proj_w = (const float*)d_in[4];
  const float* proj_b = (const float*)d_in[5];
  const float* btab   = (const float*)d_in[6];
  const int*   ridx   = (const int*)d_in[7];
  unsigned short* ws  = (unsigned short*)d_ws;
  float* out = (float*)d_out;

  const bool expanded = ws_size >= (size_t)(COMB2_OFF + COMB2_SHORTS) * 2u;

  hipLaunchKernelGGL(prep_kernel, dim3(64), dim3(256), 0, stream, qkv_w, proj_w, btab, ridx, ws);
  if (expanded) {
    hipLaunchKernelGGL(prep2_kernel, dim3(1024), dim3(256), 0, stream, mask, btab, ridx, ws + COMB2_OFF);
    hipLaunchKernelGGL(win_attn_x, dim3(8192), dim3(256), 0, stream,
                       x, qkv_b, proj_b, ws, out);
  } else {
    hipLaunchKernelGGL(win_attn_fb, dim3(8192), dim3(256), 0, stream,
                       x, mask, qkv_b, proj_b, ws, out);
  }
}

// Round 18
// 207.958 us; speedup vs baseline: 1.0418x; 1.0418x over previous
//
#include <hip/hip_runtime.h>

typedef __attribute__((ext_vector_type(8))) short short8;
typedef __attribute__((ext_vector_type(4))) short short4v;
typedef __attribute__((ext_vector_type(4))) float float4v;

#define DEV static __device__ __forceinline__

DEV float b2f(unsigned short u) { return __uint_as_float(((unsigned)u) << 16); }
DEV unsigned short f2b(float f) {
  return __builtin_bit_cast(unsigned short, static_cast<__bf16>(f));
}

#define LOG2E 1.44269504088896340736f
#define QSCALE 0.17677669529663687f  // 32^-0.5

// ws layout (2-byte units):
// [0, 65536)      weights bf16, lane-ordered fragments:
//                 [m:{q,k,v,proj}][h][kt][dc][lane][8]  (each fragment = contiguous 1KB)
//                 m=0 (W_q) pre-scaled by QSCALE*LOG2E
// [65536, 81920)  biasM bf16 [4][64 q-row][64 key] row-major, pre-scaled by LOG2E (fallback)
// [81920, +33.5M) comb2 bf16 [1024 wm][4 h][4 ci][4 ri][64 lane][4 j] = (mask+bias)*LOG2E
#define COMB2_OFF 81920
#define COMB2_SHORTS (1024u * 4u * 4096u)

// merged prep: blocks 0..63 = weights + biasM; blocks 64..1087 = comb2 (one wm each)
__global__ void prep_kernel(const float* __restrict__ qkvw, const float* __restrict__ projw,
                            const float* __restrict__ btab, const int* __restrict__ ridx,
                            const float* __restrict__ mask, unsigned short* __restrict__ ws) {
  int blk = blockIdx.x;
  if (blk < 64) {
    int t = blk * 256 + threadIdx.x;
    const int nt = 64 * 256;
    for (int i = t; i < 65536; i += nt) {
      int m = i >> 14, r = i & 16383;
      int e = r & 7, lane = (r >> 3) & 63, dc = (r >> 9) & 1, kt = (r >> 10) & 3, h = r >> 12;
      int row = h * 32 + dc * 16 + (lane & 15);
      int col = kt * 32 + (lane >> 4) * 8 + e;
      float v;
      if (m == 3) {
        v = projw[row * 128 + col];
      } else {
        v = qkvw[(m * 128 + row) * 128 + col];
        if (m == 0) v *= QSCALE * LOG2E;
      }
      ws[i] = f2b(v);
    }
    for (int i = t; i < 16384; i += nt) {
      int h = i >> 12, r = i & 4095;
      ws[65536 + i] = f2b(btab[ridx[r] * 4 + h] * LOG2E);
    }
  } else {
    // comb2[wm][h][ci][ri][lane][j]: one (row,key) position per thread-iter, all 4 heads
    int wm = blk - 64;
    const float* mrow = mask + (size_t)wm * 4096;
    unsigned short* cb = ws + COMB2_OFF + (size_t)wm * 16384;
#pragma unroll 4
    for (int p = threadIdx.x; p < 4096; p += 256) {
      int row = p >> 6, key = p & 63;
      int ri = row >> 4, l15 = row & 15, ci = key >> 4, gg = (key >> 2) & 3, j = key & 3;
      int lane = gg * 16 + l15;
      float m = mrow[p];
      float4 b4 = *(const float4*)&btab[ridx[p] * 4];  // [225][4]: contiguous per-head
      int off = ((ci * 4 + ri) * 64 + lane) * 4 + j;
      cb[off] = f2b((m + b4.x) * LOG2E);
      cb[4096 + off] = f2b((m + b4.y) * LOG2E);
      cb[8192 + off] = f2b((m + b4.z) * LOG2E);
      cb[12288 + off] = f2b((m + b4.w) * LOG2E);
    }
  }
}

#define MFMA32 __builtin_amdgcn_mfma_f32_16x16x32_bf16

// ==================== EXPANDED: 16KB LDS, split passes, occ-4 ===============
__global__ __launch_bounds__(256, 4)
void win_attn_x(const float* __restrict__ x, const float* __restrict__ qkv_b,
                const float* __restrict__ proj_b, const unsigned short* __restrict__ ws,
                float* __restrict__ out) {
  // LDS (16 KB): x tile [64][128] bf16, swizzled (later attn_out)
  __shared__ short sm[8192];

  const int b = blockIdx.x;
  const int tid = threadIdx.x;
  const int h = tid >> 6;       // wave id == head
  const int lane = tid & 63;
  const int l15 = lane & 15;
  const int g = lane >> 4;
  const int g1 = g & 1, g2 = g >> 1;
  const int wm = b & 1023;

  // ---------------- phase 0: stage x only ------------------------------------
  {
    const float4* xw = (const float4*)(x + (size_t)b * 8192);
#pragma unroll
    for (int it = 0; it < 4; ++it) {
      int c = it * 256 + tid;           // 8-elem chunk 0..1023
      int row = c >> 4, ch = c & 15;
      float4 a0 = xw[c * 2], a1 = xw[c * 2 + 1];
      short8 v;
      v[0] = (short)f2b(a0.x); v[1] = (short)f2b(a0.y);
      v[2] = (short)f2b(a0.z); v[3] = (short)f2b(a0.w);
      v[4] = (short)f2b(a1.x); v[5] = (short)f2b(a1.y);
      v[6] = (short)f2b(a1.z); v[7] = (short)f2b(a1.w);
      *(short8*)&sm[row * 128 + ((ch ^ (row & 7)) << 3)] = v;
    }
  }
  __syncthreads();

#define LDA(kt, ri) (*(const short8*)&sm[(16 * (ri) + l15) * 128 + ((((kt)*4 + g) ^ (l15 & 7)) << 3)])
#define LW(mb, kt, dc) (*(const short8*)&ws[(mb) + (h << 12) + ((kt) << 10) + ((dc) << 9) + (lane << 3)])

  short8 kp8[4], qp8[4], vp8[2][2];

  // ---------------- pass k: k^T = Wk x^T + bk (swapped, kt looped) -----------
  {
    float4v acc[2][4];
#pragma unroll
    for (int dc = 0; dc < 2; ++dc) {
      float4v bk = *(const float4v*)&qkv_b[128 + h * 32 + dc * 16 + 4 * g];
#pragma unroll
      for (int ri = 0; ri < 4; ++ri)
#pragma unroll
        for (int j = 0; j < 4; ++j) acc[dc][ri][j] = bk[j];
    }
#pragma unroll 2
    for (int kt = 0; kt < 4; ++kt) {
      short8 af[4];
#pragma unroll
      for (int ri = 0; ri < 4; ++ri) af[ri] = LDA(kt, ri);
#pragma unroll
      for (int dc = 0; dc < 2; ++dc) {
        short8 wk = LW(16384, kt, dc);
#pragma unroll
        for (int ri = 0; ri < 4; ++ri) acc[dc][ri] = MFMA32(wk, af[ri], acc[dc][ri], 0, 0, 0);
      }
    }
#pragma unroll
    for (int ci = 0; ci < 4; ++ci)
#pragma unroll
      for (int dc = 0; dc < 2; ++dc)
#pragma unroll
        for (int j = 0; j < 4; ++j) kp8[ci][4 * dc + j] = (short)f2b(acc[dc][ci][j]);
  }

  // ---------------- pass v: v = x Wv^T + bv (unswapped, kt looped) -----------
  {
    float4v acc[2][4];
#pragma unroll
    for (int dt = 0; dt < 2; ++dt) {
      float bv = qkv_b[256 + h * 32 + dt * 16 + l15];
#pragma unroll
      for (int ri = 0; ri < 4; ++ri)
#pragma unroll
        for (int j = 0; j < 4; ++j) acc[dt][ri][j] = bv;
    }
#pragma unroll 2
    for (int kt = 0; kt < 4; ++kt) {
      short8 af[4];
#pragma unroll
      for (int ri = 0; ri < 4; ++ri) af[ri] = LDA(kt, ri);
#pragma unroll
      for (int dt = 0; dt < 2; ++dt) {
        short8 wv = LW(32768, kt, dt);
#pragma unroll
        for (int ri = 0; ri < 4; ++ri) acc[dt][ri] = MFMA32(af[ri], wv, acc[dt][ri], 0, 0, 0);
      }
    }
#pragma unroll
    for (int dt = 0; dt < 2; ++dt)
#pragma unroll
      for (int ci = 0; ci < 4; ++ci)
#pragma unroll
        for (int j = 0; j < 4; ++j)
          vp8[dt][ci >> 1][4 * (ci & 1) + j] = (short)f2b(acc[dt][ci][j]);
  }

  // ---------------- pass q (kt looped) ---------------------------------------
  {
    float4v acc[2][4];
#pragma unroll
    for (int dc = 0; dc < 2; ++dc) {
      float4v bb = *(const float4v*)&qkv_b[h * 32 + dc * 16 + 4 * g];
#pragma unroll
      for (int ri = 0; ri < 4; ++ri)
#pragma unroll
        for (int j = 0; j < 4; ++j) acc[dc][ri][j] = bb[j] * (QSCALE * LOG2E);
    }
#pragma unroll 2
    for (int kt = 0; kt < 4; ++kt) {
      short8 af[4];
#pragma unroll
      for (int ri = 0; ri < 4; ++ri) af[ri] = LDA(kt, ri);
#pragma unroll
      for (int dc = 0; dc < 2; ++dc) {
        short8 w = LW(0, kt, dc);
#pragma unroll
        for (int ri = 0; ri < 4; ++ri) acc[dc][ri] = MFMA32(w, af[ri], acc[dc][ri], 0, 0, 0);
      }
    }
#pragma unroll
    for (int ri = 0; ri < 4; ++ri)
#pragma unroll
      for (int dc = 0; dc < 2; ++dc)
#pragma unroll
        for (int j = 0; j < 4; ++j) qp8[ri][4 * dc + j] = (short)f2b(acc[dc][ri][j]);
  }

  // ---------------- S' = K Q^T (K=32) + comb2(global), exp2, PV (K=32) -------
  const unsigned short* cb = ws + COMB2_OFF + ((size_t)(wm * 4 + h)) * 4096;
  float4v ot[2][4];
#pragma unroll
  for (int dt = 0; dt < 2; ++dt)
#pragma unroll
    for (int ri = 0; ri < 4; ++ri) { ot[dt][ri][0]=0.f; ot[dt][ri][1]=0.f; ot[dt][ri][2]=0.f; ot[dt][ri][3]=0.f; }
  float rs[4];
#pragma unroll
  for (int ri = 0; ri < 4; ++ri) {
    float sum = 0.f;
#pragma unroll
    for (int c2 = 0; c2 < 2; ++c2) {
      short4v pb2[2];
#pragma unroll
      for (int u = 0; u < 2; ++u) {
        int ci = 2 * c2 + u;
        short4v cm = *(const short4v*)&cb[(ci * 4 + ri) * 256 + lane * 4];
        float4v c;
#pragma unroll
        for (int j = 0; j < 4; ++j) c[j] = b2f((unsigned short)cm[j]);
        c = MFMA32(kp8[ci], qp8[ri], c, 0, 0, 0);
#pragma unroll
        for (int j = 0; j < 4; ++j) {
          float p = exp2f(c[j]);
          sum += p;
          pb2[u][j] = (short)f2b(p);
        }
      }
      short8 pb8 = __builtin_shufflevector(pb2[0], pb2[1], 0, 1, 2, 3, 4, 5, 6, 7);
      ot[0][ri] = MFMA32(vp8[0][c2], pb8, ot[0][ri], 0, 0, 0);
      ot[1][ri] = MFMA32(vp8[1][c2], pb8, ot[1][ri], 0, 0, 0);
    }
    sum += __shfl_xor(sum, 16);
    sum += __shfl_xor(sum, 32);
    rs[ri] = __builtin_amdgcn_rcpf(sum);
  }

  __syncthreads();  // all waves done reading x from LDS
#pragma unroll
  for (int dt = 0; dt < 2; ++dt) {
    int ch = 4 * h + 2 * dt + g2;
#pragma unroll
    for (int ri = 0; ri < 4; ++ri) {
      int row = 16 * ri + l15;
      short4v pv;
#pragma unroll
      for (int j = 0; j < 4; ++j) pv[j] = (short)f2b(ot[dt][ri][j] * rs[ri]);
      *(short4v*)&sm[row * 128 + ((ch ^ (row & 7)) << 3) + 4 * g1] = pv;
    }
  }
  __syncthreads();

  // ---------------- output projection (kt looped), C init = proj_b -----------
  float4v po[2][4];
#pragma unroll
  for (int oc = 0; oc < 2; ++oc) {
    float4v pb4 = *(const float4v*)&proj_b[h * 32 + oc * 16 + 4 * g];
#pragma unroll
    for (int ri = 0; ri < 4; ++ri)
#pragma unroll
      for (int j = 0; j < 4; ++j) po[oc][ri][j] = pb4[j];
  }
#pragma unroll 2
  for (int kt = 0; kt < 4; ++kt) {
    short8 af[4];
#pragma unroll
    for (int ri = 0; ri < 4; ++ri) af[ri] = LDA(kt, ri);
#pragma unroll
    for (int oc = 0; oc < 2; ++oc) {
      short8 w = LW(49152, kt, oc);
#pragma unroll
      for (int ri = 0; ri < 4; ++ri)
        po[oc][ri] = MFMA32(w, af[ri], po[oc][ri], 0, 0, 0);
    }
  }
  float* ob = out + (size_t)b * 8192;
#pragma unroll
  for (int oc = 0; oc < 2; ++oc)
#pragma unroll
    for (int ri = 0; ri < 4; ++ri) {
      int row = 16 * ri + l15;
      float4 o = make_float4(po[oc][ri][0], po[oc][ri][1], po[oc][ri][2], po[oc][ri][3]);
      *(float4*)&ob[row * 128 + h * 32 + oc * 16 + 4 * g] = o;
    }
#undef LDA
#undef LW
}

// ==================== FALLBACK: R15 exact (48KB LDS, in-block combine) ======
__global__ __launch_bounds__(256, 3)
void win_attn_fb(const float* __restrict__ x, const float* __restrict__ mask,
                 const float* __restrict__ qkv_b, const float* __restrict__ proj_b,
                 const unsigned short* __restrict__ ws, float* __restrict__ out) {
  __shared__ short sm[24576];
  const int b = blockIdx.x;
  const int tid = threadIdx.x;
  const int h = tid >> 6;
  const int lane = tid & 63;
  const int l15 = lane & 15;
  const int g = lane >> 4;
  const int g1 = g & 1, g2 = g >> 1;
  const int wm = b & 1023;
  {
    const float4* xw = (const float4*)(x + (size_t)b * 8192);
#pragma unroll
    for (int it = 0; it < 4; ++it) {
      int c = it * 256 + tid;
      int row = c >> 4, ch = c & 15;
      float4 a0 = xw[c * 2], a1 = xw[c * 2 + 1];
      short8 v;
      v[0] = (short)f2b(a0.x); v[1] = (short)f2b(a0.y);
      v[2] = (short)f2b(a0.z); v[3] = (short)f2b(a0.w);
      v[4] = (short)f2b(a1.x); v[5] = (short)f2b(a1.y);
      v[6] = (short)f2b(a1.z); v[7] = (short)f2b(a1.w);
      *(short8*)&sm[row * 128 + ((ch ^ (row & 7)) << 3)] = v;
    }
    const float* mrow = mask + (size_t)wm * 4096;
    const unsigned short* bt = ws + 65536 + h * 4096;
    short* cs = &sm[8192 + h * 4096];
#pragma unroll 4
    for (int it = 0; it < 16; ++it) {
      int fi = it * 64 + lane;
      int row = fi >> 4, j0 = (fi & 15) << 2;
      float4 m4 = *(const float4*)&mrow[fi * 4];
      const unsigned short* bp = bt + row * 64 + j0;
      short4v v;
      v[0] = (short)f2b(__builtin_fmaf(m4.x, LOG2E, b2f(bp[0])));
      v[1] = (short)f2b(__builtin_fmaf(m4.y, LOG2E, b2f(bp[1])));
      v[2] = (short)f2b(__builtin_fmaf(m4.z, LOG2E, b2f(bp[2])));
      v[3] = (short)f2b(__builtin_fmaf(m4.w, LOG2E, b2f(bp[3])));
      *(short4v*)&cs[row * 64 + (((j0 >> 3) ^ (row & 7)) << 3) + (j0 & 7)] = v;
    }
  }
  __syncthreads();
#define LDA(kt, ri) (*(const short8*)&sm[(16 * (ri) + l15) * 128 + ((((kt)*4 + g) ^ (l15 & 7)) << 3)])
#define LW(mb, kt, dc) (*(const short8*)&ws[(mb) + (h << 12) + ((kt) << 10) + ((dc) << 9) + (lane << 3)])
  short8 kp8[4], qp8[4], vp8[2][2];
  {
    float4v acck[2][4], accv[2][4];
#pragma unroll
    for (int dc = 0; dc < 2; ++dc) {
      float4v bk = *(const float4v*)&qkv_b[128 + h * 32 + dc * 16 + 4 * g];
      float bv = qkv_b[256 + h * 32 + dc * 16 + l15];
#pragma unroll
      for (int ri = 0; ri < 4; ++ri)
#pragma unroll
        for (int j = 0; j < 4; ++j) { acck[dc][ri][j] = bk[j]; accv[dc][ri][j] = bv; }
    }
#pragma unroll 2
    for (int kt = 0; kt < 4; ++kt) {
      short8 af[4];
#pragma unroll
      for (int ri = 0; ri < 4; ++ri) af[ri] = LDA(kt, ri);
#pragma unroll
      for (int dc = 0; dc < 2; ++dc) {
        short8 wk = LW(16384, kt, dc);
#pragma unroll
        for (int ri = 0; ri < 4; ++ri) acck[dc][ri] = MFMA32(wk, af[ri], acck[dc][ri], 0, 0, 0);
      }
#pragma unroll
      for (int dt = 0; dt < 2; ++dt) {
        short8 wv = LW(32768, kt, dt);
#pragma unroll
        for (int ri = 0; ri < 4; ++ri) accv[dt][ri] = MFMA32(af[ri], wv, accv[dt][ri], 0, 0, 0);
      }
    }
#pragma unroll
    for (int ci = 0; ci < 4; ++ci)
#pragma unroll
      for (int dc = 0; dc < 2; ++dc)
#pragma unroll
        for (int j = 0; j < 4; ++j) kp8[ci][4 * dc + j] = (short)f2b(acck[dc][ci][j]);
#pragma unroll
    for (int dt = 0; dt < 2; ++dt)
#pragma unroll
      for (int ci = 0; ci < 4; ++ci)
#pragma unroll
        for (int j = 0; j < 4; ++j)
          vp8[dt][ci >> 1][4 * (ci & 1) + j] = (short)f2b(accv[dt][ci][j]);
  }
  {
    float4v acc[2][4];
#pragma unroll
    for (int dc = 0; dc < 2; ++dc) {
      float4v bb = *(const float4v*)&qkv_b[h * 32 + dc * 16 + 4 * g];
#pragma unroll
      for (int ri = 0; ri < 4; ++ri)
#pragma unroll
        for (int j = 0; j < 4; ++j) acc[dc][ri][j] = bb[j] * (QSCALE * LOG2E);
    }
#pragma unroll 2
    for (int kt = 0; kt < 4; ++kt) {
      short8 af[4];
#pragma unroll
      for (int ri = 0; ri < 4; ++ri) af[ri] = LDA(kt, ri);
#pragma unroll
      for (int dc = 0; dc < 2; ++dc) {
        short8 w = LW(0, kt, dc);
#pragma unroll
        for (int ri = 0; ri < 4; ++ri) acc[dc][ri] = MFMA32(w, af[ri], acc[dc][ri], 0, 0, 0);
      }
    }
#pragma unroll
    for (int ri = 0; ri < 4; ++ri)
#pragma unroll
      for (int dc = 0; dc < 2; ++dc)
#pragma unroll
        for (int j = 0; j < 4; ++j) qp8[ri][4 * dc + j] = (short)f2b(acc[dc][ri][j]);
  }
  const short* cs = &sm[8192 + h * 4096];
  float4v ot[2][4];
#pragma unroll
  for (int dt = 0; dt < 2; ++dt)
#pragma unroll
    for (int ri = 0; ri < 4; ++ri) { ot[dt][ri][0]=0.f; ot[dt][ri][1]=0.f; ot[dt][ri][2]=0.f; ot[dt][ri][3]=0.f; }
  float rs[4];
#pragma unroll
  for (int ri = 0; ri < 4; ++ri) {
    int row = 16 * ri + l15;
    float sum = 0.f;
    short4v pb[4];
#pragma unroll
    for (int ci = 0; ci < 4; ++ci) {
      short4v cm = *(const short4v*)&cs[row * 64 + (((2 * ci + g2) ^ (row & 7)) << 3) + 4 * g1];
      float4v c;
#pragma unroll
      for (int j = 0; j < 4; ++j) c[j] = b2f((unsigned short)cm[j]);
      c = MFMA32(kp8[ci], qp8[ri], c, 0, 0, 0);
#pragma unroll
      for (int j = 0; j < 4; ++j) {
        float p = exp2f(c[j]);
        sum += p;
        pb[ci][j] = (short)f2b(p);
      }
    }
#pragma unroll
    for (int c2 = 0; c2 < 2; ++c2) {
      short8 pb8 = __builtin_shufflevector(pb[2 * c2], pb[2 * c2 + 1], 0, 1, 2, 3, 4, 5, 6, 7);
      ot[0][ri] = MFMA32(vp8[0][c2], pb8, ot[0][ri], 0, 0, 0);
      ot[1][ri] = MFMA32(vp8[1][c2], pb8, ot[1][ri], 0, 0, 0);
    }
    sum += __shfl_xor(sum, 16);
    sum += __shfl_xor(sum, 32);
    rs[ri] = __builtin_amdgcn_rcpf(sum);
  }
  __syncthreads();
#pragma unroll
  for (int dt = 0; dt < 2; ++dt) {
    int ch = 4 * h + 2 * dt + g2;
#pragma unroll
    for (int ri = 0; ri < 4; ++ri) {
      int row = 16 * ri + l15;
      short4v pv;
#pragma unroll
      for (int j = 0; j < 4; ++j) pv[j] = (short)f2b(ot[dt][ri][j] * rs[ri]);
      *(short4v*)&sm[row * 128 + ((ch ^ (row & 7)) << 3) + 4 * g1] = pv;
    }
  }
  __syncthreads();
  float4v po[2][4];
#pragma unroll
  for (int oc = 0; oc < 2; ++oc) {
    float4v pb4 = *(const float4v*)&proj_b[h * 32 + oc * 16 + 4 * g];
#pragma unroll
    for (int ri = 0; ri < 4; ++ri)
#pragma unroll
      for (int j = 0; j < 4; ++j) po[oc][ri][j] = pb4[j];
  }
#pragma unroll 2
  for (int kt = 0; kt < 4; ++kt) {
    short8 af[4];
#pragma unroll
    for (int ri = 0; ri < 4; ++ri) af[ri] = LDA(kt, ri);
#pragma unroll
    for (int oc = 0; oc < 2; ++oc) {
      short8 w = LW(49152, kt, oc);
#pragma unroll
      for (int ri = 0; ri < 4; ++ri)
        po[oc][ri] = MFMA32(w, af[ri], po[oc][ri], 0, 0, 0);
    }
  }
  float* ob = out + (size_t)b * 8192;
#pragma unroll
  for (int oc = 0; oc < 2; ++oc)
#pragma unroll
    for (int ri = 0; ri < 4; ++ri) {
      int row = 16 * ri + l15;
      float4 o = make_float4(po[oc][ri][0], po[oc][ri][1], po[oc][ri][2], po[oc][ri][3]);
      *(float4*)&ob[row * 128 + h * 32 + oc * 16 + 4 * g] = o;
    }
#undef LDA
#undef LW
}

extern "C" void kernel_launch(void* const* d_in, const int* in_sizes, int n_in,
                              void* d_out, int out_size, void* d_ws, size_t ws_size,
                              hipStream_t stream) {
  const float* x      = (const float*)d_in[0];
  const float* mask   = (const float*)d_in[1];
  const float* qkv_w  = (const float*)d_in[2];
  const float* qkv_b  = (const float*)d_in[3];
  const float* proj_w = (const float*)d_in[4];
  const float* proj_b = (const float*)d_in[5];
  const float* btab   = (const float*)d_in[6];
  const int*   ridx   = (const int*)d_in[7];
  unsigned short* ws  = (unsigned short*)d_ws;
  float* out = (float*)d_out;

  const bool expanded = ws_size >= (size_t)(COMB2_OFF + COMB2_SHORTS) * 2u;

  hipLaunchKernelGGL(prep_kernel, dim3(expanded ? 1088 : 64), dim3(256), 0, stream,
                     qkv_w, proj_w, btab, ridx, mask, ws);
  if (expanded) {
    hipLaunchKernelGGL(win_attn_x, dim3(8192), dim3(256), 0, stream,
                       x, qkv_b, proj_b, ws, out);
  } else {
    hipLaunchKernelGGL(win_attn_fb, dim3(8192), dim3(256), 0, stream,
                       x, mask, qkv_b, proj_b, ws, out);
  }
}

// Round 19
// 206.127 us; speedup vs baseline: 1.0511x; 1.0089x over previous
//
#include <hip/hip_runtime.h>

typedef __attribute__((ext_vector_type(8))) short short8;
typedef __attribute__((ext_vector_type(4))) short short4v;
typedef __attribute__((ext_vector_type(4))) float float4v;

#define DEV static __device__ __forceinline__

DEV float b2f(unsigned short u) { return __uint_as_float(((unsigned)u) << 16); }
DEV unsigned short f2b(float f) {
  return __builtin_bit_cast(unsigned short, static_cast<__bf16>(f));
}

#define LOG2E 1.44269504088896340736f
#define QSCALE 0.17677669529663687f  // 32^-0.5

// ws layout (2-byte units):
// [0, 65536)      weights bf16, lane-ordered fragments:
//                 [m:{q,k,v,proj}][h][kt][dc][lane][8]  (each fragment = contiguous 1KB)
//                 m=0 (W_q) pre-scaled by QSCALE*LOG2E
// [65536, 81920)  biasM bf16 [4][64 q-row][64 key] row-major, pre-scaled by LOG2E (fallback)
// [81920, +33.5M) comb2 bf16 [1024 wm][4 h][4 ci][4 ri][64 lane][4 j] = (mask+bias)*LOG2E
#define COMB2_OFF 81920
#define COMB2_SHORTS (1024u * 4u * 4096u)

// merged prep: blocks 0..63 = weights + biasM; blocks 64..1087 = comb2 (one wm each)
__global__ void prep_kernel(const float* __restrict__ qkvw, const float* __restrict__ projw,
                            const float* __restrict__ btab, const int* __restrict__ ridx,
                            const float* __restrict__ mask, unsigned short* __restrict__ ws) {
  int blk = blockIdx.x;
  if (blk < 64) {
    int t = blk * 256 + threadIdx.x;
    const int nt = 64 * 256;
    for (int i = t; i < 65536; i += nt) {
      int m = i >> 14, r = i & 16383;
      int e = r & 7, lane = (r >> 3) & 63, dc = (r >> 9) & 1, kt = (r >> 10) & 3, h = r >> 12;
      int row = h * 32 + dc * 16 + (lane & 15);
      int col = kt * 32 + (lane >> 4) * 8 + e;
      float v;
      if (m == 3) {
        v = projw[row * 128 + col];
      } else {
        v = qkvw[(m * 128 + row) * 128 + col];
        if (m == 0) v *= QSCALE * LOG2E;
      }
      ws[i] = f2b(v);
    }
    for (int i = t; i < 16384; i += nt) {
      int h = i >> 12, r = i & 4095;
      ws[65536 + i] = f2b(btab[ridx[r] * 4 + h] * LOG2E);
    }
  } else {
    // comb2[wm][h][ci][ri][lane][j]: one (row,key) position per thread-iter, all 4 heads
    int wm = blk - 64;
    const float* mrow = mask + (size_t)wm * 4096;
    unsigned short* cb = ws + COMB2_OFF + (size_t)wm * 16384;
#pragma unroll 4
    for (int p = threadIdx.x; p < 4096; p += 256) {
      int row = p >> 6, key = p & 63;
      int ri = row >> 4, l15 = row & 15, ci = key >> 4, gg = (key >> 2) & 3, j = key & 3;
      int lane = gg * 16 + l15;
      float m = mrow[p];
      float4 b4 = *(const float4*)&btab[ridx[p] * 4];  // [225][4]: contiguous per-head
      int off = ((ci * 4 + ri) * 64 + lane) * 4 + j;
      cb[off] = f2b((m + b4.x) * LOG2E);
      cb[4096 + off] = f2b((m + b4.y) * LOG2E);
      cb[8192 + off] = f2b((m + b4.z) * LOG2E);
      cb[12288 + off] = f2b((m + b4.w) * LOG2E);
    }
  }
}

#define MFMA32 __builtin_amdgcn_mfma_f32_16x16x32_bf16

// ==================== EXPANDED: 16KB LDS, occ-4, spill-free =================
__global__ __launch_bounds__(256, 4)
void win_attn_x(const float* __restrict__ x, const float* __restrict__ qkv_b,
                const float* __restrict__ proj_b, const unsigned short* __restrict__ ws,
                float* __restrict__ out) {
  // LDS (16 KB): x tile [64][128] bf16, swizzled (later attn_out)
  __shared__ short sm[8192];

  const int b = blockIdx.x;
  const int tid = threadIdx.x;
  const int h = tid >> 6;       // wave id == head
  const int lane = tid & 63;
  const int l15 = lane & 15;
  const int g = lane >> 4;
  const int g1 = g & 1, g2 = g >> 1;
  const int wm = b & 1023;

  // ---------------- phase 0: stage x only ------------------------------------
  {
    const float4* xw = (const float4*)(x + (size_t)b * 8192);
#pragma unroll
    for (int it = 0; it < 4; ++it) {
      int c = it * 256 + tid;           // 8-elem chunk 0..1023
      int row = c >> 4, ch = c & 15;
      float4 a0 = xw[c * 2], a1 = xw[c * 2 + 1];
      short8 v;
      v[0] = (short)f2b(a0.x); v[1] = (short)f2b(a0.y);
      v[2] = (short)f2b(a0.z); v[3] = (short)f2b(a0.w);
      v[4] = (short)f2b(a1.x); v[5] = (short)f2b(a1.y);
      v[6] = (short)f2b(a1.z); v[7] = (short)f2b(a1.w);
      *(short8*)&sm[row * 128 + ((ch ^ (row & 7)) << 3)] = v;
    }
  }
  __syncthreads();

#define LDA(kt, ri) (*(const short8*)&sm[(16 * (ri) + l15) * 128 + ((((kt)*4 + g) ^ (l15 & 7)) << 3)])
#define LW(mb, kt, dc) (*(const short8*)&ws[(mb) + (h << 12) + ((kt) << 10) + ((dc) << 9) + (lane << 3)])

  short8 kp8[4], qp8[4], vp8[2][2];

  // ---------------- pass k: k^T = Wk x^T + bk (swapped, kt looped) -----------
  {
    float4v acc[2][4];
#pragma unroll
    for (int dc = 0; dc < 2; ++dc) {
      float4v bk = *(const float4v*)&qkv_b[128 + h * 32 + dc * 16 + 4 * g];
#pragma unroll
      for (int ri = 0; ri < 4; ++ri)
#pragma unroll
        for (int j = 0; j < 4; ++j) acc[dc][ri][j] = bk[j];
    }
#pragma unroll 2
    for (int kt = 0; kt < 4; ++kt) {
      short8 af[4];
#pragma unroll
      for (int ri = 0; ri < 4; ++ri) af[ri] = LDA(kt, ri);
#pragma unroll
      for (int dc = 0; dc < 2; ++dc) {
        short8 wk = LW(16384, kt, dc);
#pragma unroll
        for (int ri = 0; ri < 4; ++ri) acc[dc][ri] = MFMA32(wk, af[ri], acc[dc][ri], 0, 0, 0);
      }
    }
#pragma unroll
    for (int ci = 0; ci < 4; ++ci)
#pragma unroll
      for (int dc = 0; dc < 2; ++dc)
#pragma unroll
        for (int j = 0; j < 4; ++j) kp8[ci][4 * dc + j] = (short)f2b(acc[dc][ci][j]);
  }

  // ---------------- pass v: v = x Wv^T + bv (unswapped, kt looped) -----------
  {
    float4v acc[2][4];
#pragma unroll
    for (int dt = 0; dt < 2; ++dt) {
      float bv = qkv_b[256 + h * 32 + dt * 16 + l15];
#pragma unroll
      for (int ri = 0; ri < 4; ++ri)
#pragma unroll
        for (int j = 0; j < 4; ++j) acc[dt][ri][j] = bv;
    }
#pragma unroll 2
    for (int kt = 0; kt < 4; ++kt) {
      short8 af[4];
#pragma unroll
      for (int ri = 0; ri < 4; ++ri) af[ri] = LDA(kt, ri);
#pragma unroll
      for (int dt = 0; dt < 2; ++dt) {
        short8 wv = LW(32768, kt, dt);
#pragma unroll
        for (int ri = 0; ri < 4; ++ri) acc[dt][ri] = MFMA32(af[ri], wv, acc[dt][ri], 0, 0, 0);
      }
    }
#pragma unroll
    for (int dt = 0; dt < 2; ++dt)
#pragma unroll
      for (int ci = 0; ci < 4; ++ci)
#pragma unroll
        for (int j = 0; j < 4; ++j)
          vp8[dt][ci >> 1][4 * (ci & 1) + j] = (short)f2b(acc[dt][ci][j]);
  }

  // ---------------- pass q (kt looped) ---------------------------------------
  {
    float4v acc[2][4];
#pragma unroll
    for (int dc = 0; dc < 2; ++dc) {
      float4v bb = *(const float4v*)&qkv_b[h * 32 + dc * 16 + 4 * g];
#pragma unroll
      for (int ri = 0; ri < 4; ++ri)
#pragma unroll
        for (int j = 0; j < 4; ++j) acc[dc][ri][j] = bb[j] * (QSCALE * LOG2E);
    }
#pragma unroll 2
    for (int kt = 0; kt < 4; ++kt) {
      short8 af[4];
#pragma unroll
      for (int ri = 0; ri < 4; ++ri) af[ri] = LDA(kt, ri);
#pragma unroll
      for (int dc = 0; dc < 2; ++dc) {
        short8 w = LW(0, kt, dc);
#pragma unroll
        for (int ri = 0; ri < 4; ++ri) acc[dc][ri] = MFMA32(w, af[ri], acc[dc][ri], 0, 0, 0);
      }
    }
#pragma unroll
    for (int ri = 0; ri < 4; ++ri)
#pragma unroll
      for (int dc = 0; dc < 2; ++dc)
#pragma unroll
        for (int j = 0; j < 4; ++j) qp8[ri][4 * dc + j] = (short)f2b(acc[dc][ri][j]);
  }

  // ---------------- S' = K Q^T (K=32) + comb2(global), exp2, PV (K=32) -------
  // normalization folded into the ri loop: no persistent rs[] array
  const unsigned short* cb = ws + COMB2_OFF + ((size_t)(wm * 4 + h)) * 4096;
  float4v ot[2][4];
#pragma unroll
  for (int dt = 0; dt < 2; ++dt)
#pragma unroll
    for (int ri = 0; ri < 4; ++ri) { ot[dt][ri][0]=0.f; ot[dt][ri][1]=0.f; ot[dt][ri][2]=0.f; ot[dt][ri][3]=0.f; }
#pragma unroll
  for (int ri = 0; ri < 4; ++ri) {
    float sum = 0.f;
#pragma unroll
    for (int c2 = 0; c2 < 2; ++c2) {
      short4v pbA, pbB;
#pragma unroll
      for (int u = 0; u < 2; ++u) {
        int ci = 2 * c2 + u;
        short4v cm = *(const short4v*)&cb[(ci * 4 + ri) * 256 + lane * 4];
        float4v c;
#pragma unroll
        for (int j = 0; j < 4; ++j) c[j] = b2f((unsigned short)cm[j]);
        c = MFMA32(kp8[ci], qp8[ri], c, 0, 0, 0);
#pragma unroll
        for (int j = 0; j < 4; ++j) {
          float p = exp2f(c[j]);
          sum += p;
          if (u == 0) pbA[j] = (short)f2b(p); else pbB[j] = (short)f2b(p);
        }
      }
      short8 pb8 = __builtin_shufflevector(pbA, pbB, 0, 1, 2, 3, 4, 5, 6, 7);
      ot[0][ri] = MFMA32(vp8[0][c2], pb8, ot[0][ri], 0, 0, 0);
      ot[1][ri] = MFMA32(vp8[1][c2], pb8, ot[1][ri], 0, 0, 0);
    }
    sum += __shfl_xor(sum, 16);
    sum += __shfl_xor(sum, 32);
    float rs = __builtin_amdgcn_rcpf(sum);
#pragma unroll
    for (int dt = 0; dt < 2; ++dt)
#pragma unroll
      for (int j = 0; j < 4; ++j) ot[dt][ri][j] *= rs;
  }

  __syncthreads();  // all waves done reading x from LDS
#pragma unroll
  for (int dt = 0; dt < 2; ++dt) {
    int ch = 4 * h + 2 * dt + g2;
#pragma unroll
    for (int ri = 0; ri < 4; ++ri) {
      int row = 16 * ri + l15;
      short4v pv;
#pragma unroll
      for (int j = 0; j < 4; ++j) pv[j] = (short)f2b(ot[dt][ri][j]);
      *(short4v*)&sm[row * 128 + ((ch ^ (row & 7)) << 3) + 4 * g1] = pv;
    }
  }
  __syncthreads();

  // ---------------- output projection (kt looped), C init = proj_b -----------
  float4v po[2][4];
#pragma unroll
  for (int oc = 0; oc < 2; ++oc) {
    float4v pb4 = *(const float4v*)&proj_b[h * 32 + oc * 16 + 4 * g];
#pragma unroll
    for (int ri = 0; ri < 4; ++ri)
#pragma unroll
      for (int j = 0; j < 4; ++j) po[oc][ri][j] = pb4[j];
  }
#pragma unroll 2
  for (int kt = 0; kt < 4; ++kt) {
    short8 af[4];
#pragma unroll
    for (int ri = 0; ri < 4; ++ri) af[ri] = LDA(kt, ri);
#pragma unroll
    for (int oc = 0; oc < 2; ++oc) {
      short8 w = LW(49152, kt, oc);
#pragma unroll
      for (int ri = 0; ri < 4; ++ri)
        po[oc][ri] = MFMA32(w, af[ri], po[oc][ri], 0, 0, 0);
    }
  }
  float* ob = out + (size_t)b * 8192;
#pragma unroll
  for (int oc = 0; oc < 2; ++oc)
#pragma unroll
    for (int ri = 0; ri < 4; ++ri) {
      int row = 16 * ri + l15;
      float4 o = make_float4(po[oc][ri][0], po[oc][ri][1], po[oc][ri][2], po[oc][ri][3]);
      *(float4*)&ob[row * 128 + h * 32 + oc * 16 + 4 * g] = o;
    }
#undef LDA
#undef LW
}

// ==================== FALLBACK: R15 exact (48KB LDS, in-block combine) ======
__global__ __launch_bounds__(256, 3)
void win_attn_fb(const float* __restrict__ x, const float* __restrict__ mask,
                 const float* __restrict__ qkv_b, const float* __restrict__ proj_b,
                 const unsigned short* __restrict__ ws, float* __restrict__ out) {
  __shared__ short sm[24576];
  const int b = blockIdx.x;
  const int tid = threadIdx.x;
  const int h = tid >> 6;
  const int lane = tid & 63;
  const int l15 = lane & 15;
  const int g = lane >> 4;
  const int g1 = g & 1, g2 = g >> 1;
  const int wm = b & 1023;
  {
    const float4* xw = (const float4*)(x + (size_t)b * 8192);
#pragma unroll
    for (int it = 0; it < 4; ++it) {
      int c = it * 256 + tid;
      int row = c >> 4, ch = c & 15;
      float4 a0 = xw[c * 2], a1 = xw[c * 2 + 1];
      short8 v;
      v[0] = (short)f2b(a0.x); v[1] = (short)f2b(a0.y);
      v[2] = (short)f2b(a0.z); v[3] = (short)f2b(a0.w);
      v[4] = (short)f2b(a1.x); v[5] = (short)f2b(a1.y);
      v[6] = (short)f2b(a1.z); v[7] = (short)f2b(a1.w);
      *(short8*)&sm[row * 128 + ((ch ^ (row & 7)) << 3)] = v;
    }
    const float* mrow = mask + (size_t)wm * 4096;
    const unsigned short* bt = ws + 65536 + h * 4096;
    short* cs = &sm[8192 + h * 4096];
#pragma unroll 4
    for (int it = 0; it < 16; ++it) {
      int fi = it * 64 + lane;
      int row = fi >> 4, j0 = (fi & 15) << 2;
      float4 m4 = *(const float4*)&mrow[fi * 4];
      const unsigned short* bp = bt + row * 64 + j0;
      short4v v;
      v[0] = (short)f2b(__builtin_fmaf(m4.x, LOG2E, b2f(bp[0])));
      v[1] = (short)f2b(__builtin_fmaf(m4.y, LOG2E, b2f(bp[1])));
      v[2] = (short)f2b(__builtin_fmaf(m4.z, LOG2E, b2f(bp[2])));
      v[3] = (short)f2b(__builtin_fmaf(m4.w, LOG2E, b2f(bp[3])));
      *(short4v*)&cs[row * 64 + (((j0 >> 3) ^ (row & 7)) << 3) + (j0 & 7)] = v;
    }
  }
  __syncthreads();
#define LDA(kt, ri) (*(const short8*)&sm[(16 * (ri) + l15) * 128 + ((((kt)*4 + g) ^ (l15 & 7)) << 3)])
#define LW(mb, kt, dc) (*(const short8*)&ws[(mb) + (h << 12) + ((kt) << 10) + ((dc) << 9) + (lane << 3)])
  short8 kp8[4], qp8[4], vp8[2][2];
  {
    float4v acck[2][4], accv[2][4];
#pragma unroll
    for (int dc = 0; dc < 2; ++dc) {
      float4v bk = *(const float4v*)&qkv_b[128 + h * 32 + dc * 16 + 4 * g];
      float bv = qkv_b[256 + h * 32 + dc * 16 + l15];
#pragma unroll
      for (int ri = 0; ri < 4; ++ri)
#pragma unroll
        for (int j = 0; j < 4; ++j) { acck[dc][ri][j] = bk[j]; accv[dc][ri][j] = bv; }
    }
#pragma unroll 2
    for (int kt = 0; kt < 4; ++kt) {
      short8 af[4];
#pragma unroll
      for (int ri = 0; ri < 4; ++ri) af[ri] = LDA(kt, ri);
#pragma unroll
      for (int dc = 0; dc < 2; ++dc) {
        short8 wk = LW(16384, kt, dc);
#pragma unroll
        for (int ri = 0; ri < 4; ++ri) acck[dc][ri] = MFMA32(wk, af[ri], acck[dc][ri], 0, 0, 0);
      }
#pragma unroll
      for (int dt = 0; dt < 2; ++dt) {
        short8 wv = LW(32768, kt, dt);
#pragma unroll
        for (int ri = 0; ri < 4; ++ri) accv[dt][ri] = MFMA32(af[ri], wv, accv[dt][ri], 0, 0, 0);
      }
    }
#pragma unroll
    for (int ci = 0; ci < 4; ++ci)
#pragma unroll
      for (int dc = 0; dc < 2; ++dc)
#pragma unroll
        for (int j = 0; j < 4; ++j) kp8[ci][4 * dc + j] = (short)f2b(acck[dc][ci][j]);
#pragma unroll
    for (int dt = 0; dt < 2; ++dt)
#pragma unroll
      for (int ci = 0; ci < 4; ++ci)
#pragma unroll
        for (int j = 0; j < 4; ++j)
          vp8[dt][ci >> 1][4 * (ci & 1) + j] = (short)f2b(accv[dt][ci][j]);
  }
  {
    float4v acc[2][4];
#pragma unroll
    for (int dc = 0; dc < 2; ++dc) {
      float4v bb = *(const float4v*)&qkv_b[h * 32 + dc * 16 + 4 * g];
#pragma unroll
      for (int ri = 0; ri < 4; ++ri)
#pragma unroll
        for (int j = 0; j < 4; ++j) acc[dc][ri][j] = bb[j] * (QSCALE * LOG2E);
    }
#pragma unroll 2
    for (int kt = 0; kt < 4; ++kt) {
      short8 af[4];
#pragma unroll
      for (int ri = 0; ri < 4; ++ri) af[ri] = LDA(kt, ri);
#pragma unroll
      for (int dc = 0; dc < 2; ++dc) {
        short8 w = LW(0, kt, dc);
#pragma unroll
        for (int ri = 0; ri < 4; ++ri) acc[dc][ri] = MFMA32(w, af[ri], acc[dc][ri], 0, 0, 0);
      }
    }
#pragma unroll
    for (int ri = 0; ri < 4; ++ri)
#pragma unroll
      for (int dc = 0; dc < 2; ++dc)
#pragma unroll
        for (int j = 0; j < 4; ++j) qp8[ri][4 * dc + j] = (short)f2b(acc[dc][ri][j]);
  }
  const short* cs = &sm[8192 + h * 4096];
  float4v ot[2][4];
#pragma unroll
  for (int dt = 0; dt < 2; ++dt)
#pragma unroll
    for (int ri = 0; ri < 4; ++ri) { ot[dt][ri][0]=0.f; ot[dt][ri][1]=0.f; ot[dt][ri][2]=0.f; ot[dt][ri][3]=0.f; }
  float rs[4];
#pragma unroll
  for (int ri = 0; ri < 4; ++ri) {
    int row = 16 * ri + l15;
    float sum = 0.f;
    short4v pb[4];
#pragma unroll
    for (int ci = 0; ci < 4; ++ci) {
      short4v cm = *(const short4v*)&cs[row * 64 + (((2 * ci + g2) ^ (row & 7)) << 3) + 4 * g1];
      float4v c;
#pragma unroll
      for (int j = 0; j < 4; ++j) c[j] = b2f((unsigned short)cm[j]);
      c = MFMA32(kp8[ci], qp8[ri], c, 0, 0, 0);
#pragma unroll
      for (int j = 0; j < 4; ++j) {
        float p = exp2f(c[j]);
        sum += p;
        pb[ci][j] = (short)f2b(p);
      }
    }
#pragma unroll
    for (int c2 = 0; c2 < 2; ++c2) {
      short8 pb8 = __builtin_shufflevector(pb[2 * c2], pb[2 * c2 + 1], 0, 1, 2, 3, 4, 5, 6, 7);
      ot[0][ri] = MFMA32(vp8[0][c2], pb8, ot[0][ri], 0, 0, 0);
      ot[1][ri] = MFMA32(vp8[1][c2], pb8, ot[1][ri], 0, 0, 0);
    }
    sum += __shfl_xor(sum, 16);
    sum += __shfl_xor(sum, 32);
    rs[ri] = __builtin_amdgcn_rcpf(sum);
  }
  __syncthreads();
#pragma unroll
  for (int dt = 0; dt < 2; ++dt) {
    int ch = 4 * h + 2 * dt + g2;
#pragma unroll
    for (int ri = 0; ri < 4; ++ri) {
      int row = 16 * ri + l15;
      short4v pv;
#pragma unroll
      for (int j = 0; j < 4; ++j) pv[j] = (short)f2b(ot[dt][ri][j] * rs[ri]);
      *(short4v*)&sm[row * 128 + ((ch ^ (row & 7)) << 3) + 4 * g1] = pv;
    }
  }
  __syncthreads();
  float4v po[2][4];
#pragma unroll
  for (int oc = 0; oc < 2; ++oc) {
    float4v pb4 = *(const float4v*)&proj_b[h * 32 + oc * 16 + 4 * g];
#pragma unroll
    for (int ri = 0; ri < 4; ++ri)
#pragma unroll
      for (int j = 0; j < 4; ++j) po[oc][ri][j] = pb4[j];
  }
#pragma unroll 2
  for (int kt = 0; kt < 4; ++kt) {
    short8 af[4];
#pragma unroll
    for (int ri = 0; ri < 4; ++ri) af[ri] = LDA(kt, ri);
#pragma unroll
    for (int oc = 0; oc < 2; ++oc) {
      short8 w = LW(49152, kt, oc);
#pragma unroll
      for (int ri = 0; ri < 4; ++ri)
        po[oc][ri] = MFMA32(w, af[ri], po[oc][ri], 0, 0, 0);
    }
  }
  float* ob = out + (size_t)b * 8192;
#pragma unroll
  for (int oc = 0; oc < 2; ++oc)
#pragma unroll
    for (int ri = 0; ri < 4; ++ri) {
      int row = 16 * ri + l15;
      float4 o = make_float4(po[oc][ri][0], po[oc][ri][1], po[oc][ri][2], po[oc][ri][3]);
      *(float4*)&ob[row * 128 + h * 32 + oc * 16 + 4 * g] = o;
    }
#undef LDA
#undef LW
}

extern "C" void kernel_launch(void* const* d_in, const int* in_sizes, int n_in,
                              void* d_out, int out_size, void* d_ws, size_t ws_size,
                              hipStream_t stream) {
  const float* x      = (const float*)d_in[0];
  const float* mask   = (const float*)d_in[1];
  const float* qkv_w  = (const float*)d_in[2];
  const float* qkv_b  = (const float*)d_in[3];
  const float* proj_w = (const float*)d_in[4];
  const float* proj_b = (const float*)d_in[5];
  const float* btab   = (const float*)d_in[6];
  const int*   ridx   = (const int*)d_in[7];
  unsigned short* ws  = (unsigned short*)d_ws;
  float* out = (float*)d_out;

  const bool expanded = ws_size >= (size_t)(COMB2_OFF + COMB2_SHORTS) * 2u;

  hipLaunchKernelGGL(prep_kernel, dim3(expanded ? 1088 : 64), dim3(256), 0, stream,
                     qkv_w, proj_w, btab, ridx, mask, ws);
  if (expanded) {
    hipLaunchKernelGGL(win_attn_x, dim3(8192), dim3(256), 0, stream,
                       x, qkv_b, proj_b, ws, out);
  } else {
    hipLaunchKernelGGL(win_attn_fb, dim3(8192), dim3(256), 0, stream,
                       x, mask, qkv_b, proj_b, ws, out);
  }
}

// Round 20
// 190.994 us; speedup vs baseline: 1.1343x; 1.0792x over previous
//
#include <hip/hip_runtime.h>

typedef __attribute__((ext_vector_type(8))) short short8;
typedef __attribute__((ext_vector_type(4))) short short4v;
typedef __attribute__((ext_vector_type(4))) float float4v;

#define DEV static __device__ __forceinline__

DEV float b2f(unsigned short u) { return __uint_as_float(((unsigned)u) << 16); }
DEV unsigned short f2b(float f) {
  return __builtin_bit_cast(unsigned short, static_cast<__bf16>(f));
}

#define LOG2E 1.44269504088896340736f
#define QSCALE 0.17677669529663687f  // 32^-0.5

// ws layout (2-byte units):
// [0, 65536)      weights bf16, lane-ordered fragments:
//                 [m:{q,k,v,proj}][h][kt][dc][lane][8]  (each fragment = contiguous 1KB)
//                 m=0 (W_q) pre-scaled by QSCALE*LOG2E
// [65536, 81920)  biasM bf16 [4][64 q-row][64 key] row-major, pre-scaled by LOG2E (fallback)
// [81920, +33.5M) comb2 bf16 [1024 wm][4 h][4 ci][4 ri][64 lane][4 j] = (mask+bias)*LOG2E
#define COMB2_OFF 81920
#define COMB2_SHORTS (1024u * 4u * 4096u)

// merged prep: blocks 0..63 = weights + biasM; blocks 64..1087 = comb2 (one wm each)
__global__ void prep_kernel(const float* __restrict__ qkvw, const float* __restrict__ projw,
                            const float* __restrict__ btab, const int* __restrict__ ridx,
                            const float* __restrict__ mask, unsigned short* __restrict__ ws) {
  int blk = blockIdx.x;
  if (blk < 64) {
    int t = blk * 256 + threadIdx.x;
    const int nt = 64 * 256;
    for (int i = t; i < 65536; i += nt) {
      int m = i >> 14, r = i & 16383;
      int e = r & 7, lane = (r >> 3) & 63, dc = (r >> 9) & 1, kt = (r >> 10) & 3, h = r >> 12;
      int row = h * 32 + dc * 16 + (lane & 15);
      int col = kt * 32 + (lane >> 4) * 8 + e;
      float v;
      if (m == 3) {
        v = projw[row * 128 + col];
      } else {
        v = qkvw[(m * 128 + row) * 128 + col];
        if (m == 0) v *= QSCALE * LOG2E;
      }
      ws[i] = f2b(v);
    }
    for (int i = t; i < 16384; i += nt) {
      int h = i >> 12, r = i & 4095;
      ws[65536 + i] = f2b(btab[ridx[r] * 4 + h] * LOG2E);
    }
  } else {
    // comb2[wm][h][ci][ri][lane][j]: one (row,key) position per thread-iter, all 4 heads
    int wm = blk - 64;
    const float* mrow = mask + (size_t)wm * 4096;
    unsigned short* cb = ws + COMB2_OFF + (size_t)wm * 16384;
#pragma unroll 4
    for (int p = threadIdx.x; p < 4096; p += 256) {
      int row = p >> 6, key = p & 63;
      int ri = row >> 4, l15 = row & 15, ci = key >> 4, gg = (key >> 2) & 3, j = key & 3;
      int lane = gg * 16 + l15;
      float m = mrow[p];
      float4 b4 = *(const float4*)&btab[ridx[p] * 4];  // [225][4]: contiguous per-head
      int off = ((ci * 4 + ri) * 64 + lane) * 4 + j;
      cb[off] = f2b((m + b4.x) * LOG2E);
      cb[4096 + off] = f2b((m + b4.y) * LOG2E);
      cb[8192 + off] = f2b((m + b4.z) * LOG2E);
      cb[12288 + off] = f2b((m + b4.w) * LOG2E);
    }
  }
}

#define MFMA32 __builtin_amdgcn_mfma_f32_16x16x32_bf16
#define MFMA16 __builtin_amdgcn_mfma_f32_16x16x16bf16_1k

// ==================== EXPANDED: 32KB LDS (x + V), occ-4, V-in-LDS ===========
__global__ __launch_bounds__(256, 4)
void win_attn_x(const float* __restrict__ x, const float* __restrict__ qkv_b,
                const float* __restrict__ proj_b, const unsigned short* __restrict__ ws,
                float* __restrict__ out) {
  // LDS (32 KB): [0,8192)      x tile [64][128] bf16, swizzled (later attn_out)
  //              [8192,16384)  V fragments, per head 2048 shorts, linear per-lane:
  //                            [(dt*4+ci)*256 + lane*4 + j] = V[key=16ci+4g+j][d=16dt+l15]
  __shared__ short sm[16384];

  const int b = blockIdx.x;
  const int tid = threadIdx.x;
  const int h = tid >> 6;       // wave id == head
  const int lane = tid & 63;
  const int l15 = lane & 15;
  const int g = lane >> 4;
  const int g1 = g & 1, g2 = g >> 1;
  const int wm = b & 1023;

  // ---------------- phase 0: stage x only ------------------------------------
  {
    const float4* xw = (const float4*)(x + (size_t)b * 8192);
#pragma unroll
    for (int it = 0; it < 4; ++it) {
      int c = it * 256 + tid;           // 8-elem chunk 0..1023
      int row = c >> 4, ch = c & 15;
      float4 a0 = xw[c * 2], a1 = xw[c * 2 + 1];
      short8 v;
      v[0] = (short)f2b(a0.x); v[1] = (short)f2b(a0.y);
      v[2] = (short)f2b(a0.z); v[3] = (short)f2b(a0.w);
      v[4] = (short)f2b(a1.x); v[5] = (short)f2b(a1.y);
      v[6] = (short)f2b(a1.z); v[7] = (short)f2b(a1.w);
      *(short8*)&sm[row * 128 + ((ch ^ (row & 7)) << 3)] = v;
    }
  }
  __syncthreads();

#define LDA(kt, ri) (*(const short8*)&sm[(16 * (ri) + l15) * 128 + ((((kt)*4 + g) ^ (l15 & 7)) << 3)])
#define LW(mb, kt, dc) (*(const short8*)&ws[(mb) + (h << 12) + ((kt) << 10) + ((dc) << 9) + (lane << 3)])

  short8 kp8[4], qp8[4];
  short* vls = &sm[8192 + h * 2048];

  // ---------------- pass k: k^T = Wk x^T + bk (swapped, kt looped) -----------
  {
    float4v acc[2][4];
#pragma unroll
    for (int dc = 0; dc < 2; ++dc) {
      float4v bk = *(const float4v*)&qkv_b[128 + h * 32 + dc * 16 + 4 * g];
#pragma unroll
      for (int ri = 0; ri < 4; ++ri)
#pragma unroll
        for (int j = 0; j < 4; ++j) acc[dc][ri][j] = bk[j];
    }
#pragma unroll 2
    for (int kt = 0; kt < 4; ++kt) {
      short8 af[4];
#pragma unroll
      for (int ri = 0; ri < 4; ++ri) af[ri] = LDA(kt, ri);
#pragma unroll
      for (int dc = 0; dc < 2; ++dc) {
        short8 wk = LW(16384, kt, dc);
#pragma unroll
        for (int ri = 0; ri < 4; ++ri) acc[dc][ri] = MFMA32(wk, af[ri], acc[dc][ri], 0, 0, 0);
      }
    }
#pragma unroll
    for (int ci = 0; ci < 4; ++ci)
#pragma unroll
      for (int dc = 0; dc < 2; ++dc)
#pragma unroll
        for (int j = 0; j < 4; ++j) kp8[ci][4 * dc + j] = (short)f2b(acc[dc][ci][j]);
  }

  // ---------------- pass v: v = x Wv^T + bv -> LDS (same-wave) ---------------
  {
    float4v acc[2][4];
#pragma unroll
    for (int dt = 0; dt < 2; ++dt) {
      float bv = qkv_b[256 + h * 32 + dt * 16 + l15];
#pragma unroll
      for (int ri = 0; ri < 4; ++ri)
#pragma unroll
        for (int j = 0; j < 4; ++j) acc[dt][ri][j] = bv;
    }
#pragma unroll 2
    for (int kt = 0; kt < 4; ++kt) {
      short8 af[4];
#pragma unroll
      for (int ri = 0; ri < 4; ++ri) af[ri] = LDA(kt, ri);
#pragma unroll
      for (int dt = 0; dt < 2; ++dt) {
        short8 wv = LW(32768, kt, dt);
#pragma unroll
        for (int ri = 0; ri < 4; ++ri) acc[dt][ri] = MFMA32(af[ri], wv, acc[dt][ri], 0, 0, 0);
      }
    }
    // park V fragments in LDS at per-lane addresses (same wave reads them in PV)
#pragma unroll
    for (int dt = 0; dt < 2; ++dt)
#pragma unroll
      for (int ci = 0; ci < 4; ++ci) {
        short4v pv;
#pragma unroll
        for (int j = 0; j < 4; ++j) pv[j] = (short)f2b(acc[dt][ci][j]);
        *(short4v*)&vls[(dt * 4 + ci) * 256 + lane * 4] = pv;
      }
  }

  // ---------------- pass q (kt looped) ---------------------------------------
  {
    float4v acc[2][4];
#pragma unroll
    for (int dc = 0; dc < 2; ++dc) {
      float4v bb = *(const float4v*)&qkv_b[h * 32 + dc * 16 + 4 * g];
#pragma unroll
      for (int ri = 0; ri < 4; ++ri)
#pragma unroll
        for (int j = 0; j < 4; ++j) acc[dc][ri][j] = bb[j] * (QSCALE * LOG2E);
    }
#pragma unroll 2
    for (int kt = 0; kt < 4; ++kt) {
      short8 af[4];
#pragma unroll
      for (int ri = 0; ri < 4; ++ri) af[ri] = LDA(kt, ri);
#pragma unroll
      for (int dc = 0; dc < 2; ++dc) {
        short8 w = LW(0, kt, dc);
#pragma unroll
        for (int ri = 0; ri < 4; ++ri) acc[dc][ri] = MFMA32(w, af[ri], acc[dc][ri], 0, 0, 0);
      }
    }
#pragma unroll
    for (int ri = 0; ri < 4; ++ri)
#pragma unroll
      for (int dc = 0; dc < 2; ++dc)
#pragma unroll
        for (int j = 0; j < 4; ++j) qp8[ri][4 * dc + j] = (short)f2b(acc[dc][ri][j]);
  }

  // ---------------- S' = K Q^T (K=32) + comb2, exp2, PV (K=16 from LDS) ------
  const unsigned short* cb = ws + COMB2_OFF + ((size_t)(wm * 4 + h)) * 4096;
  float4v ot[2][4];
#pragma unroll
  for (int dt = 0; dt < 2; ++dt)
#pragma unroll
    for (int ri = 0; ri < 4; ++ri) { ot[dt][ri][0]=0.f; ot[dt][ri][1]=0.f; ot[dt][ri][2]=0.f; ot[dt][ri][3]=0.f; }
#pragma unroll
  for (int ri = 0; ri < 4; ++ri) {
    float sum = 0.f;
#pragma unroll
    for (int ci = 0; ci < 4; ++ci) {
      short4v cm = *(const short4v*)&cb[(ci * 4 + ri) * 256 + lane * 4];
      float4v c;
#pragma unroll
      for (int j = 0; j < 4; ++j) c[j] = b2f((unsigned short)cm[j]);
      c = MFMA32(kp8[ci], qp8[ri], c, 0, 0, 0);
      short4v pb4;
#pragma unroll
      for (int j = 0; j < 4; ++j) {
        float p = exp2f(c[j]);
        sum += p;
        pb4[j] = (short)f2b(p);
      }
      short4v v0 = *(const short4v*)&vls[(0 * 4 + ci) * 256 + lane * 4];
      short4v v1 = *(const short4v*)&vls[(1 * 4 + ci) * 256 + lane * 4];
      ot[0][ri] = MFMA16(v0, pb4, ot[0][ri], 0, 0, 0);
      ot[1][ri] = MFMA16(v1, pb4, ot[1][ri], 0, 0, 0);
    }
    sum += __shfl_xor(sum, 16);
    sum += __shfl_xor(sum, 32);
    float rs = __builtin_amdgcn_rcpf(sum);
#pragma unroll
    for (int dt = 0; dt < 2; ++dt)
#pragma unroll
      for (int j = 0; j < 4; ++j) ot[dt][ri][j] *= rs;
  }

  __syncthreads();  // all waves done reading x from LDS
#pragma unroll
  for (int dt = 0; dt < 2; ++dt) {
    int ch = 4 * h + 2 * dt + g2;
#pragma unroll
    for (int ri = 0; ri < 4; ++ri) {
      int row = 16 * ri + l15;
      short4v pv;
#pragma unroll
      for (int j = 0; j < 4; ++j) pv[j] = (short)f2b(ot[dt][ri][j]);
      *(short4v*)&sm[row * 128 + ((ch ^ (row & 7)) << 3) + 4 * g1] = pv;
    }
  }
  __syncthreads();

  // ---------------- output projection (kt looped), C init = proj_b -----------
  float4v po[2][4];
#pragma unroll
  for (int oc = 0; oc < 2; ++oc) {
    float4v pb4 = *(const float4v*)&proj_b[h * 32 + oc * 16 + 4 * g];
#pragma unroll
    for (int ri = 0; ri < 4; ++ri)
#pragma unroll
      for (int j = 0; j < 4; ++j) po[oc][ri][j] = pb4[j];
  }
#pragma unroll 2
  for (int kt = 0; kt < 4; ++kt) {
    short8 af[4];
#pragma unroll
    for (int ri = 0; ri < 4; ++ri) af[ri] = LDA(kt, ri);
#pragma unroll
    for (int oc = 0; oc < 2; ++oc) {
      short8 w = LW(49152, kt, oc);
#pragma unroll
      for (int ri = 0; ri < 4; ++ri)
        po[oc][ri] = MFMA32(w, af[ri], po[oc][ri], 0, 0, 0);
    }
  }
  float* ob = out + (size_t)b * 8192;
#pragma unroll
  for (int oc = 0; oc < 2; ++oc)
#pragma unroll
    for (int ri = 0; ri < 4; ++ri) {
      int row = 16 * ri + l15;
      float4 o = make_float4(po[oc][ri][0], po[oc][ri][1], po[oc][ri][2], po[oc][ri][3]);
      *(float4*)&ob[row * 128 + h * 32 + oc * 16 + 4 * g] = o;
    }
#undef LDA
#undef LW
}

// ==================== FALLBACK: R15 exact (48KB LDS, in-block combine) ======
__global__ __launch_bounds__(256, 3)
void win_attn_fb(const float* __restrict__ x, const float* __restrict__ mask,
                 const float* __restrict__ qkv_b, const float* __restrict__ proj_b,
                 const unsigned short* __restrict__ ws, float* __restrict__ out) {
  __shared__ short sm[24576];
  const int b = blockIdx.x;
  const int tid = threadIdx.x;
  const int h = tid >> 6;
  const int lane = tid & 63;
  const int l15 = lane & 15;
  const int g = lane >> 4;
  const int g1 = g & 1, g2 = g >> 1;
  const int wm = b & 1023;
  {
    const float4* xw = (const float4*)(x + (size_t)b * 8192);
#pragma unroll
    for (int it = 0; it < 4; ++it) {
      int c = it * 256 + tid;
      int row = c >> 4, ch = c & 15;
      float4 a0 = xw[c * 2], a1 = xw[c * 2 + 1];
      short8 v;
      v[0] = (short)f2b(a0.x); v[1] = (short)f2b(a0.y);
      v[2] = (short)f2b(a0.z); v[3] = (short)f2b(a0.w);
      v[4] = (short)f2b(a1.x); v[5] = (short)f2b(a1.y);
      v[6] = (short)f2b(a1.z); v[7] = (short)f2b(a1.w);
      *(short8*)&sm[row * 128 + ((ch ^ (row & 7)) << 3)] = v;
    }
    const float* mrow = mask + (size_t)wm * 4096;
    const unsigned short* bt = ws + 65536 + h * 4096;
    short* cs = &sm[8192 + h * 4096];
#pragma unroll 4
    for (int it = 0; it < 16; ++it) {
      int fi = it * 64 + lane;
      int row = fi >> 4, j0 = (fi & 15) << 2;
      float4 m4 = *(const float4*)&mrow[fi * 4];
      const unsigned short* bp = bt + row * 64 + j0;
      short4v v;
      v[0] = (short)f2b(__builtin_fmaf(m4.x, LOG2E, b2f(bp[0])));
      v[1] = (short)f2b(__builtin_fmaf(m4.y, LOG2E, b2f(bp[1])));
      v[2] = (short)f2b(__builtin_fmaf(m4.z, LOG2E, b2f(bp[2])));
      v[3] = (short)f2b(__builtin_fmaf(m4.w, LOG2E, b2f(bp[3])));
      *(short4v*)&cs[row * 64 + (((j0 >> 3) ^ (row & 7)) << 3) + (j0 & 7)] = v;
    }
  }
  __syncthreads();
#define LDA(kt, ri) (*(const short8*)&sm[(16 * (ri) + l15) * 128 + ((((kt)*4 + g) ^ (l15 & 7)) << 3)])
#define LW(mb, kt, dc) (*(const short8*)&ws[(mb) + (h << 12) + ((kt) << 10) + ((dc) << 9) + (lane << 3)])
  short8 kp8[4], qp8[4], vp8[2][2];
  {
    float4v acck[2][4], accv[2][4];
#pragma unroll
    for (int dc = 0; dc < 2; ++dc) {
      float4v bk = *(const float4v*)&qkv_b[128 + h * 32 + dc * 16 + 4 * g];
      float bv = qkv_b[256 + h * 32 + dc * 16 + l15];
#pragma unroll
      for (int ri = 0; ri < 4; ++ri)
#pragma unroll
        for (int j = 0; j < 4; ++j) { acck[dc][ri][j] = bk[j]; accv[dc][ri][j] = bv; }
    }
#pragma unroll 2
    for (int kt = 0; kt < 4; ++kt) {
      short8 af[4];
#pragma unroll
      for (int ri = 0; ri < 4; ++ri) af[ri] = LDA(kt, ri);
#pragma unroll
      for (int dc = 0; dc < 2; ++dc) {
        short8 wk = LW(16384, kt, dc);
#pragma unroll
        for (int ri = 0; ri < 4; ++ri) acck[dc][ri] = MFMA32(wk, af[ri], acck[dc][ri], 0, 0, 0);
      }
#pragma unroll
      for (int dt = 0; dt < 2; ++dt) {
        short8 wv = LW(32768, kt, dt);
#pragma unroll
        for (int ri = 0; ri < 4; ++ri) accv[dt][ri] = MFMA32(af[ri], wv, accv[dt][ri], 0, 0, 0);
      }
    }
#pragma unroll
    for (int ci = 0; ci < 4; ++ci)
#pragma unroll
      for (int dc = 0; dc < 2; ++dc)
#pragma unroll
        for (int j = 0; j < 4; ++j) kp8[ci][4 * dc + j] = (short)f2b(acck[dc][ci][j]);
#pragma unroll
    for (int dt = 0; dt < 2; ++dt)
#pragma unroll
      for (int ci = 0; ci < 4; ++ci)
#pragma unroll
        for (int j = 0; j < 4; ++j)
          vp8[dt][ci >> 1][4 * (ci & 1) + j] = (short)f2b(accv[dt][ci][j]);
  }
  {
    float4v acc[2][4];
#pragma unroll
    for (int dc = 0; dc < 2; ++dc) {
      float4v bb = *(const float4v*)&qkv_b[h * 32 + dc * 16 + 4 * g];
#pragma unroll
      for (int ri = 0; ri < 4; ++ri)
#pragma unroll
        for (int j = 0; j < 4; ++j) acc[dc][ri][j] = bb[j] * (QSCALE * LOG2E);
    }
#pragma unroll 2
    for (int kt = 0; kt < 4; ++kt) {
      short8 af[4];
#pragma unroll
      for (int ri = 0; ri < 4; ++ri) af[ri] = LDA(kt, ri);
#pragma unroll
      for (int dc = 0; dc < 2; ++dc) {
        short8 w = LW(0, kt, dc);
#pragma unroll
        for (int ri = 0; ri < 4; ++ri) acc[dc][ri] = MFMA32(w, af[ri], acc[dc][ri], 0, 0, 0);
      }
    }
#pragma unroll
    for (int ri = 0; ri < 4; ++ri)
#pragma unroll
      for (int dc = 0; dc < 2; ++dc)
#pragma unroll
        for (int j = 0; j < 4; ++j) qp8[ri][4 * dc + j] = (short)f2b(acc[dc][ri][j]);
  }
  const short* cs = &sm[8192 + h * 4096];
  float4v ot[2][4];
#pragma unroll
  for (int dt = 0; dt < 2; ++dt)
#pragma unroll
    for (int ri = 0; ri < 4; ++ri) { ot[dt][ri][0]=0.f; ot[dt][ri][1]=0.f; ot[dt][ri][2]=0.f; ot[dt][ri][3]=0.f; }
  float rs[4];
#pragma unroll
  for (int ri = 0; ri < 4; ++ri) {
    int row = 16 * ri + l15;
    float sum = 0.f;
    short4v pb[4];
#pragma unroll
    for (int ci = 0; ci < 4; ++ci) {
      short4v cm = *(const short4v*)&cs[row * 64 + (((2 * ci + g2) ^ (row & 7)) << 3) + 4 * g1];
      float4v c;
#pragma unroll
      for (int j = 0; j < 4; ++j) c[j] = b2f((unsigned short)cm[j]);
      c = MFMA32(kp8[ci], qp8[ri], c, 0, 0, 0);
#pragma unroll
      for (int j = 0; j < 4; ++j) {
        float p = exp2f(c[j]);
        sum += p;
        pb[ci][j] = (short)f2b(p);
      }
    }
#pragma unroll
    for (int c2 = 0; c2 < 2; ++c2) {
      short8 pb8 = __builtin_shufflevector(pb[2 * c2], pb[2 * c2 + 1], 0, 1, 2, 3, 4, 5, 6, 7);
      ot[0][ri] = MFMA32(vp8[0][c2], pb8, ot[0][ri], 0, 0, 0);
      ot[1][ri] = MFMA32(vp8[1][c2], pb8, ot[1][ri], 0, 0, 0);
    }
    sum += __shfl_xor(sum, 16);
    sum += __shfl_xor(sum, 32);
    rs[ri] = __builtin_amdgcn_rcpf(sum);
  }
  __syncthreads();
#pragma unroll
  for (int dt = 0; dt < 2; ++dt) {
    int ch = 4 * h + 2 * dt + g2;
#pragma unroll
    for (int ri = 0; ri < 4; ++ri) {
      int row = 16 * ri + l15;
      short4v pv;
#pragma unroll
      for (int j = 0; j < 4; ++j) pv[j] = (short)f2b(ot[dt][ri][j] * rs[ri]);
      *(short4v*)&sm[row * 128 + ((ch ^ (row & 7)) << 3) + 4 * g1] = pv;
    }
  }
  __syncthreads();
  float4v po[2][4];
#pragma unroll
  for (int oc = 0; oc < 2; ++oc) {
    float4v pb4 = *(const float4v*)&proj_b[h * 32 + oc * 16 + 4 * g];
#pragma unroll
    for (int ri = 0; ri < 4; ++ri)
#pragma unroll
      for (int j = 0; j < 4; ++j) po[oc][ri][j] = pb4[j];
  }
#pragma unroll 2
  for (int kt = 0; kt < 4; ++kt) {
    short8 af[4];
#pragma unroll
    for (int ri = 0; ri < 4; ++ri) af[ri] = LDA(kt, ri);
#pragma unroll
    for (int oc = 0; oc < 2; ++oc) {
      short8 w = LW(49152, kt, oc);
#pragma unroll
      for (int ri = 0; ri < 4; ++ri)
        po[oc][ri] = MFMA32(w, af[ri], po[oc][ri], 0, 0, 0);
    }
  }
  float* ob = out + (size_t)b * 8192;
#pragma unroll
  for (int oc = 0; oc < 2; ++oc)
#pragma unroll
    for (int ri = 0; ri < 4; ++ri) {
      int row = 16 * ri + l15;
      float4 o = make_float4(po[oc][ri][0], po[oc][ri][1], po[oc][ri][2], po[oc][ri][3]);
      *(float4*)&ob[row * 128 + h * 32 + oc * 16 + 4 * g] = o;
    }
#undef LDA
#undef LW
}

extern "C" void kernel_launch(void* const* d_in, const int* in_sizes, int n_in,
                              void* d_out, int out_size, void* d_ws, size_t ws_size,
                              hipStream_t stream) {
  const float* x      = (const float*)d_in[0];
  const float* mask   = (const float*)d_in[1];
  const float* qkv_w  = (const float*)d_in[2];
  const float* qkv_b  = (const float*)d_in[3];
  const float* proj_w = (const float*)d_in[4];
  const float* proj_b = (const float*)d_in[5];
  const float* btab   = (const float*)d_in[6];
  const int*   ridx   = (const int*)d_in[7];
  unsigned short* ws  = (unsigned short*)d_ws;
  float* out = (float*)d_out;

  const bool expanded = ws_size >= (size_t)(COMB2_OFF + COMB2_SHORTS) * 2u;

  hipLaunchKernelGGL(prep_kernel, dim3(expanded ? 1088 : 64), dim3(256), 0, stream,
                     qkv_w, proj_w, btab, ridx, mask, ws);
  if (expanded) {
    hipLaunchKernelGGL(win_attn_x, dim3(8192), dim3(256), 0, stream,
                       x, qkv_b, proj_b, ws, out);
  } else {
    hipLaunchKernelGGL(win_attn_fb, dim3(8192), dim3(256), 0, stream,
                       x, mask, qkv_b, proj_b, ws, out);
  }
}